// Round 5
// baseline (107.593 us; speedup 1.0000x reference)
//
#include <hip/hip_runtime.h>
#include <hip/hip_bf16.h>
#include <stdint.h>

typedef __attribute__((ext_vector_type(8))) short bf16x8;
typedef __attribute__((ext_vector_type(4))) float f32x4;

#define NPOS 256
#define NROW 512
#define NCH  256
#define PSTRIDE 262144   // bytes per position panel: 512 rows * 256 ch * 2B

// ---------------------------------------------------------------------------
// Kernel 1: repack fp32 [i][c][p] -> bf16 X[p][i][c]   (LDS tile transpose)
// ---------------------------------------------------------------------------
__global__ __launch_bounds__(256) void k_repack(const float* __restrict__ src,
                                                const float* __restrict__ tgt,
                                                unsigned short* __restrict__ X) {
  __shared__ float tile[64 * 65];  // [c][p], +1 pad
  int bx = blockIdx.x;
  int i  = bx >> 4;
  int cb = (bx >> 2) & 3;
  int pb = bx & 3;
  int c0 = cb * 64, p0 = pb * 64;
  const float* base = (i < 256) ? (src + (size_t)i * 65536)
                                : (tgt + (size_t)(i - 256) * 65536);
  int t = threadIdx.x;
#pragma unroll
  for (int it = 0; it < 4; ++it) {
    int idx = it * 256 + t;
    int cl = idx >> 4, pq = idx & 15;                // float4 along p (coalesced)
    float4 v = *(const float4*)&base[(c0 + cl) * 256 + p0 + pq * 4];
    tile[cl * 65 + pq * 4 + 0] = v.x;
    tile[cl * 65 + pq * 4 + 1] = v.y;
    tile[cl * 65 + pq * 4 + 2] = v.z;
    tile[cl * 65 + pq * 4 + 3] = v.w;
  }
  __syncthreads();
#pragma unroll
  for (int it = 0; it < 4; ++it) {
    int idx = it * 256 + t;
    int pl = idx >> 4, cq = idx & 15;                // ushort4 along c (coalesced)
    ushort4 o;
    unsigned short* op = &o.x;
#pragma unroll
    for (int j = 0; j < 4; ++j) {
      unsigned u = __float_as_uint(tile[(cq * 4 + j) * 65 + pl]);
      op[j] = (unsigned short)((u + 0x7fffu + ((u >> 16) & 1u)) >> 16);  // RNE
    }
    *(ushort4*)&X[((size_t)(p0 + pl) * NROW + i) * NCH + c0 + cq * 4] = o;
  }
}

// ---------------------------------------------------------------------------
// Kernel 2: SQ[p*512+i] = sum_c X[p][i][c]^2
// ---------------------------------------------------------------------------
__global__ __launch_bounds__(256) void k_sq(const unsigned short* __restrict__ X,
                                            float* __restrict__ SQ) {
  int gid = blockIdx.x * 256 + threadIdx.x;
  int row = gid >> 5;
  int l = threadIdx.x & 31;
  uint4 v = *(const uint4*)(X + (size_t)row * NCH + l * 8);
  float s = 0.f;
  const unsigned* u = &v.x;
#pragma unroll
  for (int j = 0; j < 4; ++j) {
    float flo = __uint_as_float(u[j] << 16);
    float fhi = __uint_as_float(u[j] & 0xffff0000u);
    s += flo * flo + fhi * fhi;
  }
#pragma unroll
  for (int off = 16; off; off >>= 1) s += __shfl_down(s, off, 32);
  if (l == 0) SQ[row] = s;
}

// ---------------------------------------------------------------------------
// Kernel 3: fused Gram + RBF epilogue. T4 pipeline in plain HIP:
//   BK=32 double-buffer (32KB -> 4 blocks/CU), counted vmcnt (never 0 in
//   steady state), raw s_barrier, 2 positions per block (16 steps), p0's
//   epilogue overlaps p1's in-flight stages.
// LDS swizzle (BK=32, 4 x 16B slots/row): slot ^= (row>>1)&3 -> 2-way max.
// Staging: global_load_lds w=16, linear LDS dest + inverse-swizzled source.
// grid: 128 pairs * 10 upper-tri tiles = 1280 blocks, 4 waves (2x2).
// Diag tiles: wave 2 mirrors wave 1 -> skip compute, wave 1 weight x2;
//             waves with wr==wc reuse A-frags as B (Gram symmetry).
// ---------------------------------------------------------------------------
__device__ __forceinline__ int swz32(int row, int lk) {
  return row * 64 + ((lk ^ ((row >> 1) & 3)) << 4);
}

__global__ __launch_bounds__(256, 4) void k_mmd(const unsigned short* __restrict__ X,
                                                const float* __restrict__ SQ,
                                                float* __restrict__ part) {
  __shared__ unsigned short As[2][128 * 32];
  __shared__ unsigned short Bs[2][128 * 32];
  __shared__ float SQs[2][2][128];   // [pos][i/j][row]
  __shared__ float wsum[4];

  int bid = blockIdx.x;
  int bx = (bid & 7) * 160 + (bid >> 3);   // XCD swizzle (bijective: 1280 = 8*160)
  int pair = bx / 10;
  int tileid = bx - pair * 10;
  int it, jt;
  if (tileid < 4)      { it = 0; jt = tileid; }
  else if (tileid < 7) { it = 1; jt = tileid - 3; }
  else if (tileid < 9) { it = 2; jt = tileid - 5; }
  else                 { it = 3; jt = 3; }
  int p0 = pair * 2;
  int i0 = it * 128, j0 = jt * 128;
  int t = threadIdx.x;
  int lane = t & 63, w = t >> 6;
  int wr = w >> 1, wc = w & 1;
  int l15 = lane & 15, lk = lane >> 4;
  bool diag = (it == jt);
  bool skipw = diag && (w == 2);           // mirror of wave (0,1)

  const char* Xbase = (const char*)X + (size_t)p0 * PSTRIDE;
  const char* XA = Xbase + (size_t)i0 * 512;   // 512 B per row
  const char* XB = Xbase + (size_t)j0 * 512;

  // SQ -> LDS for both positions; drain lgkm so writes are visible after the
  // first pipeline barrier.
  float* SQf = &SQs[0][0][0];
#pragma unroll
  for (int q = 0; q < 2; ++q) {
    int f = q * 256 + t;
    int pos = f >> 8, ij = (f >> 7) & 1, off = f & 127;
    SQf[f] = SQ[(p0 + pos) * NROW + (ij ? j0 : i0) + off];
  }
  asm volatile("s_waitcnt lgkmcnt(0)" ::: "memory");

  // staging address components (per-lane constants)
  int srow = t >> 2;                               // row within 64-row half
  int scol = ((t & 3) ^ ((t >> 3) & 3)) * 16;      // inverse-swizzled 16B col
  int ldst = (t & ~63) * 16;                       // wave-uniform LDS dest base

  // STAGE(buf, step): 4 global_load_lds w=16 per thread (2 A + 2 B).
#define STAGE(buf, step) do {                                                  \
    const char* bA = XA + (size_t)((step) >> 3) * PSTRIDE + ((step) & 7) * 64; \
    const char* bB = XB + (size_t)((step) >> 3) * PSTRIDE + ((step) & 7) * 64; \
    _Pragma("unroll")                                                          \
    for (int r = 0; r < 2; ++r) {                                              \
      __builtin_amdgcn_global_load_lds(                                        \
        (const __attribute__((address_space(1))) void*)(bA + (size_t)(r * 64 + srow) * 512 + scol), \
        (__attribute__((address_space(3))) void*)((char*)&As[buf][0] + r * 4096 + ldst), 16, 0, 0);  \
      __builtin_amdgcn_global_load_lds(                                        \
        (const __attribute__((address_space(1))) void*)(bB + (size_t)(r * 64 + srow) * 512 + scol), \
        (__attribute__((address_space(3))) void*)((char*)&Bs[buf][0] + r * 4096 + ldst), 16, 0, 0);  \
    }                                                                          \
  } while (0)

  f32x4 zero = {0.f, 0.f, 0.f, 0.f};
  f32x4 acc[4][4];
#pragma unroll
  for (int m = 0; m < 4; ++m)
#pragma unroll
    for (int n = 0; n < 4; ++n) acc[m][n] = zero;

  STAGE(0, 0);
  STAGE(1, 1);

  // One pipeline step: wait own stage(s) (counted!), barrier (all waves'
  // stage(s) visible), read frags, drain reads, barrier (all waves done
  // reading buf), overwrite buf with stage(s+2), MFMA (overlaps flights).
#define QSTEP(s, WAITSTR) do {                                                 \
    asm volatile("s_waitcnt " WAITSTR ::: "memory");                           \
    __builtin_amdgcn_s_barrier();                                              \
    __builtin_amdgcn_sched_barrier(0);                                         \
    bf16x8 a[4], b[4];                                                         \
    if (!skipw) {                                                              \
      const char* Ab = (const char*)&As[(s) & 1][0];                           \
      const char* Bb = (const char*)&Bs[(s) & 1][0];                           \
      _Pragma("unroll")                                                        \
      for (int m = 0; m < 4; ++m)                                              \
        a[m] = *(const bf16x8*)(Ab + swz32(wr * 64 + m * 16 + l15, lk));       \
      if (diag && wr == wc) {                                                  \
        _Pragma("unroll")                                                      \
        for (int n = 0; n < 4; ++n) b[n] = a[n];                               \
      } else {                                                                 \
        _Pragma("unroll")                                                      \
        for (int n = 0; n < 4; ++n)                                            \
          b[n] = *(const bf16x8*)(Bb + swz32(wc * 64 + n * 16 + l15, lk));     \
      }                                                                        \
    }                                                                          \
    asm volatile("s_waitcnt lgkmcnt(0)" ::: "memory");                         \
    __builtin_amdgcn_sched_barrier(0);                                         \
    __builtin_amdgcn_s_barrier();                                              \
    if ((s) + 2 < 16) STAGE((s) & 1, (s) + 2);                                 \
    if (!skipw) {                                                              \
      _Pragma("unroll")                                                        \
      for (int m = 0; m < 4; ++m)                                              \
        _Pragma("unroll")                                                      \
        for (int n = 0; n < 4; ++n)                                            \
          acc[m][n] = __builtin_amdgcn_mfma_f32_16x16x32_bf16(a[m], b[n], acc[m][n], 0, 0, 0); \
    }                                                                          \
  } while (0)

  // EPILOGUE(pos): D = sqi + sqj - 2c ; K = sum_b exp(-D/b), 1 exp2 + squarings
#define EPILOGUE(pos) do {                                                     \
    if (!skipw) {                                                              \
      const float c80 = 0.01803368801f;  /* log2(e)/80 */                      \
      float sqi[16], sqj[4];                                                   \
      _Pragma("unroll")                                                        \
      for (int m = 0; m < 4; ++m)                                              \
        _Pragma("unroll")                                                      \
        for (int r = 0; r < 4; ++r)                                            \
          sqi[m * 4 + r] = SQs[pos][0][wr * 64 + m * 16 + lk * 4 + r];         \
      _Pragma("unroll")                                                        \
      for (int n = 0; n < 4; ++n) sqj[n] = SQs[pos][1][wc * 64 + n * 16 + l15];\
      bool sdiag = diag && (wr == wc);                                         \
      _Pragma("unroll")                                                        \
      for (int m = 0; m < 4; ++m) {                                            \
        _Pragma("unroll")                                                      \
        for (int n = 0; n < 4; ++n) {                                          \
          _Pragma("unroll")                                                    \
          for (int r = 0; r < 4; ++r) {                                        \
            float cv = acc[m][n][r];                                           \
            float D = sqi[m * 4 + r] + sqj[n] - 2.f * cv;                      \
            float e80 = exp2f(-c80 * D);                                       \
            float e40 = e80 * e80;                                             \
            float e20 = e40 * e40;                                             \
            float e10 = e20 * e20;                                             \
            float e5  = e10 * e10;                                             \
            float e2  = e5 * e5 * e10;        /* exp(-D/2) */                  \
            float K = (e80 + e40) + (e20 + e10) + (e5 + e2);                   \
            if (sdiag && m == n) {                                             \
              if (lk * 4 + r == l15) K = 6.0f;  /* exact diagonal */           \
            }                                                                  \
            lsum += K;                                                         \
          }                                                                    \
        }                                                                      \
      }                                                                        \
    }                                                                          \
  } while (0)

  float lsum = 0.f;

  QSTEP(0,  "vmcnt(4)");  QSTEP(1,  "vmcnt(4)");  QSTEP(2,  "vmcnt(4)");
  QSTEP(3,  "vmcnt(4)");  QSTEP(4,  "vmcnt(4)");  QSTEP(5,  "vmcnt(4)");
  QSTEP(6,  "vmcnt(4)");  QSTEP(7,  "vmcnt(4)");

  EPILOGUE(0);                              // overlaps p1's in-flight stages
#pragma unroll
  for (int m = 0; m < 4; ++m)
#pragma unroll
    for (int n = 0; n < 4; ++n) acc[m][n] = zero;

  QSTEP(8,  "vmcnt(4)");  QSTEP(9,  "vmcnt(4)");  QSTEP(10, "vmcnt(4)");
  QSTEP(11, "vmcnt(4)");  QSTEP(12, "vmcnt(4)");  QSTEP(13, "vmcnt(4)");
  QSTEP(14, "vmcnt(4)");  QSTEP(15, "vmcnt(0)");

  EPILOGUE(1);
#undef STAGE
#undef QSTEP
#undef EPILOGUE

  if (diag && w == 1) lsum *= 2.0f;        // stands in for skipped mirror wave
#pragma unroll
  for (int off = 32; off; off >>= 1) lsum += __shfl_down(lsum, off, 64);
  if (lane == 0) wsum[w] = lsum;
  __syncthreads();
  if (t == 0) {
    float sgn = ((it < 2) == (jt < 2)) ? 1.0f : -1.0f;
    float tw  = diag ? 1.0f : 2.0f;        // off-diag tiles count twice
    part[bx] = sgn * tw * (wsum[0] + wsum[1] + wsum[2] + wsum[3]);
  }
}

// ---------------------------------------------------------------------------
// Kernel 4: deterministic final reduce of 1280 partials -> mean
// ---------------------------------------------------------------------------
__global__ __launch_bounds__(256) void k_reduce(const float* __restrict__ part,
                                                float* __restrict__ out) {
  __shared__ float wsum[4];
  int t = threadIdx.x;
  float s = 0.f;
#pragma unroll
  for (int i = 0; i < 5; ++i) s += part[i * 256 + t];
#pragma unroll
  for (int off = 32; off; off >>= 1) s += __shfl_down(s, off, 64);
  int lane = t & 63, w = t >> 6;
  if (lane == 0) wsum[w] = s;
  __syncthreads();
  if (t == 0) out[0] = (wsum[0] + wsum[1] + wsum[2] + wsum[3]) * (1.0f / 16777216.0f);
}

extern "C" void kernel_launch(void* const* d_in, const int* in_sizes, int n_in,
                              void* d_out, int out_size, void* d_ws, size_t ws_size,
                              hipStream_t stream) {
  (void)in_sizes; (void)n_in; (void)out_size; (void)ws_size;
  const float* src = (const float*)d_in[0];
  const float* tgt = (const float*)d_in[1];
  char* ws = (char*)d_ws;
  unsigned short* X = (unsigned short*)ws;                    // 67,108,864 B
  float* SQ   = (float*)(ws + 67108864);                      //    524,288 B
  float* PART = (float*)(ws + 67108864 + 524288);             //      5,120 B

  hipLaunchKernelGGL(k_repack, dim3(8192),  dim3(256), 0, stream, src, tgt, X);
  hipLaunchKernelGGL(k_sq,     dim3(16384), dim3(256), 0, stream, X, SQ);
  hipLaunchKernelGGL(k_mmd,    dim3(1280),  dim3(256), 0, stream, X, SQ, PART);
  hipLaunchKernelGGL(k_reduce, dim3(1),     dim3(256), 0, stream, PART, (float*)d_out);
}

// Round 6
// 95.191 us; speedup vs baseline: 1.1303x; 1.1303x over previous
//
#include <hip/hip_runtime.h>
#include <hip/hip_bf16.h>
#include <stdint.h>

typedef __attribute__((ext_vector_type(8))) short bf16x8;
typedef __attribute__((ext_vector_type(4))) float f32x4;

#define NPOS 256
#define NROW 512
#define NCH  256
#define PSTRIDE 262144   // bytes per position panel: 512 rows * 256 ch * 2B

// ---------------------------------------------------------------------------
// Kernel 1: repack fp32 [i][c][p] -> bf16 X[p][i][c]  (LDS tile transpose)
// FUSED: also accumulates SQ[p*512+i] = sum_c xbf16^2 via 16-lane reduce +
// one atomicAdd per (p,i) per block (4 contributions per address total).
// ---------------------------------------------------------------------------
__global__ __launch_bounds__(256) void k_repack(const float* __restrict__ src,
                                                const float* __restrict__ tgt,
                                                unsigned short* __restrict__ X,
                                                float* __restrict__ SQ) {
  __shared__ float tile[64 * 65];  // [c][p], +1 pad
  int bx = blockIdx.x;
  int i  = bx >> 4;
  int cb = (bx >> 2) & 3;
  int pb = bx & 3;
  int c0 = cb * 64, p0 = pb * 64;
  const float* base = (i < 256) ? (src + (size_t)i * 65536)
                                : (tgt + (size_t)(i - 256) * 65536);
  int t = threadIdx.x;
#pragma unroll
  for (int it = 0; it < 4; ++it) {
    int idx = it * 256 + t;
    int cl = idx >> 4, pq = idx & 15;                // float4 along p (coalesced)
    float4 v = *(const float4*)&base[(c0 + cl) * 256 + p0 + pq * 4];
    tile[cl * 65 + pq * 4 + 0] = v.x;
    tile[cl * 65 + pq * 4 + 1] = v.y;
    tile[cl * 65 + pq * 4 + 2] = v.z;
    tile[cl * 65 + pq * 4 + 3] = v.w;
  }
  __syncthreads();
#pragma unroll
  for (int it = 0; it < 4; ++it) {
    int idx = it * 256 + t;
    int pl = idx >> 4, cq = idx & 15;                // ushort4 along c (coalesced)
    ushort4 o;
    unsigned short* op = &o.x;
    float part = 0.f;
#pragma unroll
    for (int j = 0; j < 4; ++j) {
      unsigned u = __float_as_uint(tile[(cq * 4 + j) * 65 + pl]);
      unsigned r = (u + 0x7fffu + ((u >> 16) & 1u)) >> 16;   // RNE to bf16
      op[j] = (unsigned short)r;
      float fr = __uint_as_float(r << 16);             // squared on ROUNDED value
      part += fr * fr;
    }
    *(ushort4*)&X[((size_t)(p0 + pl) * NROW + i) * NCH + c0 + cq * 4] = o;
    // reduce over the 16 threads sharing pl (lanes differ only in bits 0..3)
#pragma unroll
    for (int m = 1; m < 16; m <<= 1) part += __shfl_xor(part, m, 64);
    if ((t & 15) == 0) atomicAdd(&SQ[(size_t)(p0 + pl) * NROW + i], part);
  }
}

// ---------------------------------------------------------------------------
// Kernel 3: fused Gram + RBF-sum epilogue, upper-triangle tiles, np=2
// position chaining. Round-2 proven step structure (STAGE -> sync -> compute
// -> sync), single buffer, no hand pipelining. Staging = global_load_lds w=16,
// linear LDS dest + inverse-swizzled source; reads apply the XOR swizzle.
// grid: 128 pairs * 10 tiles(128x128) = 1280 blocks, 4 waves (2x2).
// Diag tiles: wave 2 (mirror of wave 1) skips compute, wave 1 weight x2;
//             waves with wr==wc reuse A-frags as B (Gram symmetry).
// ---------------------------------------------------------------------------
__device__ __forceinline__ int swz(int row, int byteoff) {
  return row * 128 + (byteoff ^ ((row & 7) << 4));
}

__global__ __launch_bounds__(256) void k_mmd(const unsigned short* __restrict__ X,
                                             const float* __restrict__ SQ,
                                             float* __restrict__ part) {
  __shared__ unsigned short As[128 * 64];
  __shared__ unsigned short Bs[128 * 64];
  __shared__ float SQs[2][2][128];   // [pos][i/j][row]
  __shared__ float wsum[4];

  int bid = blockIdx.x;
  int bx = (bid & 7) * 160 + (bid >> 3);   // XCD swizzle (bijective: 1280 = 8*160)
  int pair = bx / 10;
  int tileid = bx - pair * 10;
  int it, jt;
  if (tileid < 4)      { it = 0; jt = tileid; }
  else if (tileid < 7) { it = 1; jt = tileid - 3; }
  else if (tileid < 9) { it = 2; jt = tileid - 5; }
  else                 { it = 3; jt = 3; }
  int p0 = pair * 2;
  int i0 = it * 128, j0 = jt * 128;
  int t = threadIdx.x;
  int lane = t & 63, w = t >> 6;
  int wr = w >> 1, wc = w & 1;
  int l15 = lane & 15, lk = lane >> 4;
  bool diag = (it == jt);
  bool skipw = diag && (w == 2);           // mirror of wave (0,1)
  bool areuse = diag && (wr == wc);        // Gram: B-frags == A-frags

  const char* Xbase = (const char*)X + (size_t)p0 * PSTRIDE;
  const char* XA = Xbase + (size_t)i0 * 512;   // 512 B per row
  const char* XB = Xbase + (size_t)j0 * 512;

  // SQ -> LDS for both positions (visible after the first __syncthreads)
  float* SQf = &SQs[0][0][0];
#pragma unroll
  for (int q = 0; q < 2; ++q) {
    int f = q * 256 + t;
    int pos = f >> 8, ij = (f >> 7) & 1, off = f & 127;
    SQf[f] = SQ[(size_t)(p0 + pos) * NROW + (ij ? j0 : i0) + off];
  }

  // per-lane constant source swizzle: row&7 == lane>>3 for every issued chunk
  int lrow = lane >> 3;
  int coff = ((lane & 7) ^ lrow) * 16;

#define STAGE(pos, kk)                                                         \
  {                                                                            \
    _Pragma("unroll")                                                          \
    for (int s = 0; s < 4; ++s) {                                              \
      int rbase = w * 32 + s * 8;                                              \
      const char* ga = XA + (size_t)(pos) * PSTRIDE + (size_t)(rbase + lrow) * 512 + (kk) * 128 + coff; \
      const char* gb = XB + (size_t)(pos) * PSTRIDE + (size_t)(rbase + lrow) * 512 + (kk) * 128 + coff; \
      __builtin_amdgcn_global_load_lds(                                        \
          (const __attribute__((address_space(1))) void*)ga,                   \
          (__attribute__((address_space(3))) void*)((char*)As + rbase * 128), 16, 0, 0); \
      __builtin_amdgcn_global_load_lds(                                        \
          (const __attribute__((address_space(1))) void*)gb,                   \
          (__attribute__((address_space(3))) void*)((char*)Bs + rbase * 128), 16, 0, 0); \
    }                                                                          \
  }

  float lsum = 0.f;
  const float c80 = 0.01803368801f;  // log2(e)/80
  f32x4 zero = {0.f, 0.f, 0.f, 0.f};

#pragma unroll
  for (int pos = 0; pos < 2; ++pos) {
    f32x4 acc[4][4];
#pragma unroll
    for (int m = 0; m < 4; ++m)
#pragma unroll
      for (int n = 0; n < 4; ++n) acc[m][n] = zero;

#pragma unroll
    for (int kk = 0; kk < 4; ++kk) {
      STAGE(pos, kk);
      __syncthreads();                     // drains vmcnt: staged data visible
      if (!skipw) {
#pragma unroll
        for (int ks = 0; ks < 2; ++ks) {
          bf16x8 a[4], b[4];
#pragma unroll
          for (int m = 0; m < 4; ++m)
            a[m] = *(const bf16x8*)((const char*)As + swz(wr * 64 + m * 16 + l15, ks * 64 + lk * 16));
          if (areuse) {
#pragma unroll
            for (int n = 0; n < 4; ++n) b[n] = a[n];
          } else {
#pragma unroll
            for (int n = 0; n < 4; ++n)
              b[n] = *(const bf16x8*)((const char*)Bs + swz(wc * 64 + n * 16 + l15, ks * 64 + lk * 16));
          }
#pragma unroll
          for (int m = 0; m < 4; ++m)
#pragma unroll
            for (int n = 0; n < 4; ++n)
              acc[m][n] = __builtin_amdgcn_mfma_f32_16x16x32_bf16(a[m], b[n], acc[m][n], 0, 0, 0);
        }
      }
      // epilogue for this position sits before the trailing barrier of the
      // last K-step (reads only acc + SQs; As/Bs untouched)
      if (kk == 3 && !skipw) {
        float sqi[16], sqj[4];
#pragma unroll
        for (int m = 0; m < 4; ++m)
#pragma unroll
          for (int r = 0; r < 4; ++r)
            sqi[m * 4 + r] = SQs[pos][0][wr * 64 + m * 16 + lk * 4 + r];
#pragma unroll
        for (int n = 0; n < 4; ++n) sqj[n] = SQs[pos][1][wc * 64 + n * 16 + l15];
        bool sdiag = diag && (wr == wc);
#pragma unroll
        for (int m = 0; m < 4; ++m) {
#pragma unroll
          for (int n = 0; n < 4; ++n) {
#pragma unroll
            for (int r = 0; r < 4; ++r) {
              float cv = acc[m][n][r];
              float D = sqi[m * 4 + r] + sqj[n] - 2.f * cv;
              float e80 = exp2f(-c80 * D);     // exp(-D/80)
              float e40 = e80 * e80;
              float e20 = e40 * e40;
              float e10 = e20 * e20;
              float e5  = e10 * e10;
              float e2  = e5 * e5 * e10;       // exp(-D/2)
              float K = (e80 + e40) + (e20 + e10) + (e5 + e2);
              if (sdiag && m == n) {
                if (lk * 4 + r == l15) K = 6.0f;   // exact diagonal: D==0
              }
              lsum += K;
            }
          }
        }
      }
      __syncthreads();                     // all waves done reading As/Bs
    }
  }
#undef STAGE

  if (diag && w == 1) lsum *= 2.0f;        // stands in for skipped mirror wave
#pragma unroll
  for (int off = 32; off; off >>= 1) lsum += __shfl_down(lsum, off, 64);
  if (lane == 0) wsum[w] = lsum;
  __syncthreads();
  if (t == 0) {
    float sgn = ((it < 2) == (jt < 2)) ? 1.0f : -1.0f;
    float tw  = diag ? 1.0f : 2.0f;        // off-diag tiles count twice
    part[bx] = sgn * tw * (wsum[0] + wsum[1] + wsum[2] + wsum[3]);
  }
}

// ---------------------------------------------------------------------------
// Kernel 4: deterministic final reduce of 1280 partials -> mean
// ---------------------------------------------------------------------------
__global__ __launch_bounds__(256) void k_reduce(const float* __restrict__ part,
                                                float* __restrict__ out) {
  __shared__ float wsum[4];
  int t = threadIdx.x;
  float s = 0.f;
#pragma unroll
  for (int i = 0; i < 5; ++i) s += part[i * 256 + t];
#pragma unroll
  for (int off = 32; off; off >>= 1) s += __shfl_down(s, off, 64);
  int lane = t & 63, w = t >> 6;
  if (lane == 0) wsum[w] = s;
  __syncthreads();
  if (t == 0) out[0] = (wsum[0] + wsum[1] + wsum[2] + wsum[3]) * (1.0f / 16777216.0f);
}

extern "C" void kernel_launch(void* const* d_in, const int* in_sizes, int n_in,
                              void* d_out, int out_size, void* d_ws, size_t ws_size,
                              hipStream_t stream) {
  (void)in_sizes; (void)n_in; (void)out_size; (void)ws_size;
  const float* src = (const float*)d_in[0];
  const float* tgt = (const float*)d_in[1];
  char* ws = (char*)d_ws;
  unsigned short* X = (unsigned short*)ws;                    // 67,108,864 B
  float* SQ   = (float*)(ws + 67108864);                      //    524,288 B
  float* PART = (float*)(ws + 67108864 + 524288);             //      5,120 B

  hipMemsetAsync(SQ, 0, 524288, stream);                      // atomic targets
  hipLaunchKernelGGL(k_repack, dim3(8192), dim3(256), 0, stream, src, tgt, X, SQ);
  hipLaunchKernelGGL(k_mmd,    dim3(1280), dim3(256), 0, stream, X, SQ, PART);
  hipLaunchKernelGGL(k_reduce, dim3(1),    dim3(256), 0, stream, PART, (float*)d_out);
}

// Round 7
// 92.977 us; speedup vs baseline: 1.1572x; 1.0238x over previous
//
#include <hip/hip_runtime.h>
#include <hip/hip_bf16.h>
#include <stdint.h>

typedef __attribute__((ext_vector_type(8))) short bf16x8;
typedef __attribute__((ext_vector_type(4))) float f32x4;

#define NPOS 256
#define NROW 512
#define NCH  256
#define PSTRIDE 262144   // bytes per position panel: 512 rows * 256 ch * 2B

// ---------------------------------------------------------------------------
// Kernel 1: repack fp32 [i][c][p] -> bf16 X[p][i][c]  (LDS tile transpose)
// FUSED: also accumulates SQ[p*512+i] = sum_c xbf16^2 via 16-lane reduce +
// one atomicAdd per (p,i) per block (4 contributions per address total).
// ---------------------------------------------------------------------------
__global__ __launch_bounds__(256) void k_repack(const float* __restrict__ src,
                                                const float* __restrict__ tgt,
                                                unsigned short* __restrict__ X,
                                                float* __restrict__ SQ) {
  __shared__ float tile[64 * 65];  // [c][p], +1 pad
  int bx = blockIdx.x;
  int i  = bx >> 4;
  int cb = (bx >> 2) & 3;
  int pb = bx & 3;
  int c0 = cb * 64, p0 = pb * 64;
  const float* base = (i < 256) ? (src + (size_t)i * 65536)
                                : (tgt + (size_t)(i - 256) * 65536);
  int t = threadIdx.x;
#pragma unroll
  for (int it = 0; it < 4; ++it) {
    int idx = it * 256 + t;
    int cl = idx >> 4, pq = idx & 15;                // float4 along p (coalesced)
    float4 v = *(const float4*)&base[(c0 + cl) * 256 + p0 + pq * 4];
    tile[cl * 65 + pq * 4 + 0] = v.x;
    tile[cl * 65 + pq * 4 + 1] = v.y;
    tile[cl * 65 + pq * 4 + 2] = v.z;
    tile[cl * 65 + pq * 4 + 3] = v.w;
  }
  __syncthreads();
#pragma unroll
  for (int it = 0; it < 4; ++it) {
    int idx = it * 256 + t;
    int pl = idx >> 4, cq = idx & 15;                // ushort4 along c (coalesced)
    ushort4 o;
    unsigned short* op = &o.x;
    float part = 0.f;
#pragma unroll
    for (int j = 0; j < 4; ++j) {
      unsigned u = __float_as_uint(tile[(cq * 4 + j) * 65 + pl]);
      unsigned r = (u + 0x7fffu + ((u >> 16) & 1u)) >> 16;   // RNE to bf16
      op[j] = (unsigned short)r;
      float fr = __uint_as_float(r << 16);             // squared on ROUNDED value
      part += fr * fr;
    }
    *(ushort4*)&X[((size_t)(p0 + pl) * NROW + i) * NCH + c0 + cq * 4] = o;
    // reduce over the 16 threads sharing pl (lanes differ only in bits 0..3)
#pragma unroll
    for (int m = 1; m < 16; m <<= 1) part += __shfl_xor(part, m, 64);
    if ((t & 15) == 0) atomicAdd(&SQ[(size_t)(p0 + pl) * NROW + i], part);
  }
}

// ---------------------------------------------------------------------------
// Kernel 2: fused Gram + RBF-sum epilogue, upper-triangle tiles only.
// EXACT round-2 proven structure: np=1, single buffer, STAGE -> sync ->
// compute -> sync, epilogue after the K loop. Staging = global_load_lds w=16
// with linear LDS dest + inverse-swizzled source; reads apply the XOR swizzle.
// grid: 256 pos * 10 tiles(128x128) = 2560 blocks, 4 waves (2x2).
// Diag tiles: wave 2 (mirror of wave 1) skips compute, wave 1 weight x2;
//             waves with wr==wc reuse A-frags as B (Gram symmetry).
// ---------------------------------------------------------------------------
__device__ __forceinline__ int swz(int row, int byteoff) {
  return row * 128 + (byteoff ^ ((row & 7) << 4));
}

__global__ __launch_bounds__(256, 4) void k_mmd(const unsigned short* __restrict__ X,
                                                const float* __restrict__ SQ,
                                                float* __restrict__ part) {
  __shared__ unsigned short As[128 * 64];
  __shared__ unsigned short Bs[128 * 64];
  __shared__ float SQi[128], SQj[128];
  __shared__ float wsum[4];

  int bid = blockIdx.x;
  int bx = (bid & 7) * 320 + (bid >> 3);   // XCD swizzle (bijective: 2560 = 8*320)
  int p = bx / 10;
  int tileid = bx - p * 10;
  int it, jt;
  if (tileid < 4)      { it = 0; jt = tileid; }
  else if (tileid < 7) { it = 1; jt = tileid - 3; }
  else if (tileid < 9) { it = 2; jt = tileid - 5; }
  else                 { it = 3; jt = 3; }
  int i0 = it * 128, j0 = jt * 128;
  int t = threadIdx.x;
  int lane = t & 63, w = t >> 6;
  int wr = w >> 1, wc = w & 1;
  int l15 = lane & 15, lk = lane >> 4;
  bool diag = (it == jt);
  bool skipw = diag && (w == 2);           // mirror of wave (0,1)
  bool areuse = diag && (wr == wc);        // Gram: B-frags == A-frags

  const unsigned short* Xp = X + (size_t)p * (NROW * NCH);
  const char* XA = (const char*)Xp + (size_t)i0 * 512;   // 512 B per row
  const char* XB = (const char*)Xp + (size_t)j0 * 512;

  if (t < 128) SQi[t] = SQ[p * NROW + i0 + t];
  else         SQj[t - 128] = SQ[p * NROW + j0 + (t - 128)];

  f32x4 zero = {0.f, 0.f, 0.f, 0.f};
  f32x4 acc[4][4];
#pragma unroll
  for (int m = 0; m < 4; ++m)
#pragma unroll
    for (int n = 0; n < 4; ++n) acc[m][n] = zero;

  // per-lane constant source swizzle: row&7 == lane>>3 for every issued chunk
  int lrow = lane >> 3;
  int coff = ((lane & 7) ^ lrow) * 16;

  for (int kk = 0; kk < 4; ++kk) {
#pragma unroll
    for (int s = 0; s < 4; ++s) {
      int rbase = w * 32 + s * 8;          // wave-uniform
      const char* ga = XA + (size_t)(rbase + lrow) * 512 + kk * 128 + coff;
      const char* gb = XB + (size_t)(rbase + lrow) * 512 + kk * 128 + coff;
      __builtin_amdgcn_global_load_lds(
          (const __attribute__((address_space(1))) void*)ga,
          (__attribute__((address_space(3))) void*)((char*)As + rbase * 128), 16, 0, 0);
      __builtin_amdgcn_global_load_lds(
          (const __attribute__((address_space(1))) void*)gb,
          (__attribute__((address_space(3))) void*)((char*)Bs + rbase * 128), 16, 0, 0);
    }
    __syncthreads();                       // drains vmcnt(0): staged data visible
    if (!skipw) {
#pragma unroll
      for (int ks = 0; ks < 2; ++ks) {
        bf16x8 a[4], b[4];
#pragma unroll
        for (int m = 0; m < 4; ++m)
          a[m] = *(const bf16x8*)((const char*)As + swz(wr * 64 + m * 16 + l15, ks * 64 + lk * 16));
        if (areuse) {
#pragma unroll
          for (int n = 0; n < 4; ++n) b[n] = a[n];
        } else {
#pragma unroll
          for (int n = 0; n < 4; ++n)
            b[n] = *(const bf16x8*)((const char*)Bs + swz(wc * 64 + n * 16 + l15, ks * 64 + lk * 16));
        }
#pragma unroll
        for (int m = 0; m < 4; ++m)
#pragma unroll
          for (int n = 0; n < 4; ++n)
            acc[m][n] = __builtin_amdgcn_mfma_f32_16x16x32_bf16(a[m], b[n], acc[m][n], 0, 0, 0);
      }
    }
    __syncthreads();
  }

  // epilogue: D = sqi + sqj - 2c ; K = sum_b exp(-D/b) via 1 exp2 + squarings
  float lsum = 0.f;
  if (!skipw) {
    const float c80 = 0.01803368801f;  // log2(e)/80
    float sqi[16], sqj[4];
#pragma unroll
    for (int m = 0; m < 4; ++m)
#pragma unroll
      for (int r = 0; r < 4; ++r) sqi[m * 4 + r] = SQi[wr * 64 + m * 16 + lk * 4 + r];
#pragma unroll
    for (int n = 0; n < 4; ++n) sqj[n] = SQj[wc * 64 + n * 16 + l15];

    bool sdiag = diag && (wr == wc);
#pragma unroll
    for (int m = 0; m < 4; ++m) {
#pragma unroll
      for (int n = 0; n < 4; ++n) {
#pragma unroll
        for (int r = 0; r < 4; ++r) {
          float cv = acc[m][n][r];
          float D = sqi[m * 4 + r] + sqj[n] - 2.f * cv;
          float e80 = exp2f(-c80 * D);     // exp(-D/80)
          float e40 = e80 * e80;
          float e20 = e40 * e40;
          float e10 = e20 * e20;
          float e5  = e10 * e10;
          float e2  = e5 * e5 * e10;       // exp(-D/2)
          float K = (e80 + e40) + (e20 + e10) + (e5 + e2);
          if (sdiag && m == n) {
            if (lk * 4 + r == l15) K = 6.0f;   // exact diagonal: D==0 -> K=6
          }
          lsum += K;
        }
      }
    }
    if (diag && w == 1) lsum *= 2.0f;      // stands in for skipped mirror wave
  }
#pragma unroll
  for (int off = 32; off; off >>= 1) lsum += __shfl_down(lsum, off, 64);
  if (lane == 0) wsum[w] = lsum;
  __syncthreads();
  if (t == 0) {
    float sgn = ((it < 2) == (jt < 2)) ? 1.0f : -1.0f;
    float tw  = diag ? 1.0f : 2.0f;        // off-diag tiles count twice (symmetry)
    part[bx] = sgn * tw * (wsum[0] + wsum[1] + wsum[2] + wsum[3]);
  }
}

// ---------------------------------------------------------------------------
// Kernel 3: deterministic final reduce of 2560 partials -> mean
// ---------------------------------------------------------------------------
__global__ __launch_bounds__(256) void k_reduce(const float* __restrict__ part,
                                                float* __restrict__ out) {
  __shared__ float wsum[4];
  int t = threadIdx.x;
  float s = 0.f;
#pragma unroll
  for (int i = 0; i < 10; ++i) s += part[i * 256 + t];
#pragma unroll
  for (int off = 32; off; off >>= 1) s += __shfl_down(s, off, 64);
  int lane = t & 63, w = t >> 6;
  if (lane == 0) wsum[w] = s;
  __syncthreads();
  if (t == 0) out[0] = (wsum[0] + wsum[1] + wsum[2] + wsum[3]) * (1.0f / 16777216.0f);
}

extern "C" void kernel_launch(void* const* d_in, const int* in_sizes, int n_in,
                              void* d_out, int out_size, void* d_ws, size_t ws_size,
                              hipStream_t stream) {
  (void)in_sizes; (void)n_in; (void)out_size; (void)ws_size;
  const float* src = (const float*)d_in[0];
  const float* tgt = (const float*)d_in[1];
  char* ws = (char*)d_ws;
  unsigned short* X = (unsigned short*)ws;                    // 67,108,864 B
  float* SQ   = (float*)(ws + 67108864);                      //    524,288 B
  float* PART = (float*)(ws + 67108864 + 524288);             //     10,240 B

  hipMemsetAsync(SQ, 0, 524288, stream);                      // atomic targets
  hipLaunchKernelGGL(k_repack, dim3(8192), dim3(256), 0, stream, src, tgt, X, SQ);
  hipLaunchKernelGGL(k_mmd,    dim3(2560), dim3(256), 0, stream, X, SQ, PART);
  hipLaunchKernelGGL(k_reduce, dim3(1),    dim3(256), 0, stream, PART, (float*)d_out);
}

// Round 8
// 80.528 us; speedup vs baseline: 1.3361x; 1.1546x over previous
//
#include <hip/hip_runtime.h>
#include <hip/hip_bf16.h>
#include <stdint.h>

typedef __attribute__((ext_vector_type(8))) short bf16x8;
typedef __attribute__((ext_vector_type(4))) float f32x4;

#define NPOS 256
#define NROW 512
#define NCH  256
#define PSTRIDE 262144   // bytes per position panel: 512 rows * 256 ch * 2B

// ---------------------------------------------------------------------------
// Kernel 1: repack fp32 [i][c][p] -> bf16 X[p][i][c]  (LDS tile transpose)
// FUSED SQ partials WITHOUT atomics: each (i,cb,pb) block computes
// SQP[cb][p0+pl][i] = sum over its 64 channels of round_bf16(x)^2.
// Write phase: 8 ch/thread -> 8 ds_read_b32 (2-way alias, free) + one 16 B
// global_store_dwordx4; SQ row-reduce = 3 shfl_xor hops (8 threads/row).
// ---------------------------------------------------------------------------
__global__ __launch_bounds__(256) void k_repack(const float* __restrict__ src,
                                                const float* __restrict__ tgt,
                                                unsigned short* __restrict__ X,
                                                float* __restrict__ SQP) {
  __shared__ float tile[64 * 65];  // [c][p], +1 pad
  int bx = blockIdx.x;
  int i  = bx >> 4;
  int cb = (bx >> 2) & 3;
  int pb = bx & 3;
  int c0 = cb * 64, p0 = pb * 64;
  const float* base = (i < 256) ? (src + (size_t)i * 65536)
                                : (tgt + (size_t)(i - 256) * 65536);
  int t = threadIdx.x;
#pragma unroll
  for (int it = 0; it < 4; ++it) {
    int idx = it * 256 + t;
    int cl = idx >> 4, pq = idx & 15;                // float4 along p (coalesced)
    float4 v = *(const float4*)&base[(c0 + cl) * 256 + p0 + pq * 4];
    tile[cl * 65 + pq * 4 + 0] = v.x;
    tile[cl * 65 + pq * 4 + 1] = v.y;
    tile[cl * 65 + pq * 4 + 2] = v.z;
    tile[cl * 65 + pq * 4 + 3] = v.w;
  }
  __syncthreads();
#pragma unroll
  for (int it = 0; it < 2; ++it) {
    int idx = it * 256 + t;
    int pl = idx >> 3, c8 = idx & 7;                 // 8 threads per p-row
    unsigned rr[8];
    float part = 0.f;
#pragma unroll
    for (int j = 0; j < 8; ++j) {
      unsigned u = __float_as_uint(tile[(c8 * 8 + j) * 65 + pl]);
      rr[j] = (u + 0x7fffu + ((u >> 16) & 1u)) >> 16;        // RNE to bf16
      float fr = __uint_as_float(rr[j] << 16);               // square ROUNDED value
      part += fr * fr;
    }
    uint4 o = { rr[0] | (rr[1] << 16), rr[2] | (rr[3] << 16),
                rr[4] | (rr[5] << 16), rr[6] | (rr[7] << 16) };
    *(uint4*)&X[((size_t)(p0 + pl) * NROW + i) * NCH + c0 + c8 * 8] = o;
    // row-reduce over the 8 threads sharing pl (t bits 0..2)
    part += __shfl_xor(part, 1, 64);
    part += __shfl_xor(part, 2, 64);
    part += __shfl_xor(part, 4, 64);
    if (c8 == 0)
      SQP[(size_t)cb * (NPOS * NROW) + (size_t)(p0 + pl) * NROW + i] = part;
  }
}

// ---------------------------------------------------------------------------
// Kernel 2: fused Gram + RBF-sum epilogue, upper-triangle tiles only.
// EXACT round-7 structure (best measured): np=1, single buffer, STAGE ->
// sync -> compute -> sync, epilogue after K loop, __launch_bounds__(256,4).
// Only change: SQ load sums the 4 cb-partials (coalesced, no atomics needed).
// grid: 256 pos * 10 tiles(128x128) = 2560 blocks, 4 waves (2x2).
// ---------------------------------------------------------------------------
__device__ __forceinline__ int swz(int row, int byteoff) {
  return row * 128 + (byteoff ^ ((row & 7) << 4));
}

__global__ __launch_bounds__(256, 4) void k_mmd(const unsigned short* __restrict__ X,
                                                const float* __restrict__ SQP,
                                                float* __restrict__ part) {
  __shared__ unsigned short As[128 * 64];
  __shared__ unsigned short Bs[128 * 64];
  __shared__ float SQi[128], SQj[128];
  __shared__ float wsum[4];

  int bid = blockIdx.x;
  int bx = (bid & 7) * 320 + (bid >> 3);   // XCD swizzle (bijective: 2560 = 8*320)
  int p = bx / 10;
  int tileid = bx - p * 10;
  int it, jt;
  if (tileid < 4)      { it = 0; jt = tileid; }
  else if (tileid < 7) { it = 1; jt = tileid - 3; }
  else if (tileid < 9) { it = 2; jt = tileid - 5; }
  else                 { it = 3; jt = 3; }
  int i0 = it * 128, j0 = jt * 128;
  int t = threadIdx.x;
  int lane = t & 63, w = t >> 6;
  int wr = w >> 1, wc = w & 1;
  int l15 = lane & 15, lk = lane >> 4;
  bool diag = (it == jt);
  bool skipw = diag && (w == 2);           // mirror of wave (0,1)
  bool areuse = diag && (wr == wc);        // Gram: B-frags == A-frags

  const unsigned short* Xp = X + (size_t)p * (NROW * NCH);
  const char* XA = (const char*)Xp + (size_t)i0 * 512;   // 512 B per row
  const char* XB = (const char*)Xp + (size_t)j0 * 512;

  if (t < 128) {
    size_t q = (size_t)p * NROW + i0 + t;
    SQi[t] = SQP[q] + SQP[q + 131072] + SQP[q + 262144] + SQP[q + 393216];
  } else {
    size_t q = (size_t)p * NROW + j0 + (t - 128);
    SQj[t - 128] = SQP[q] + SQP[q + 131072] + SQP[q + 262144] + SQP[q + 393216];
  }

  f32x4 zero = {0.f, 0.f, 0.f, 0.f};
  f32x4 acc[4][4];
#pragma unroll
  for (int m = 0; m < 4; ++m)
#pragma unroll
    for (int n = 0; n < 4; ++n) acc[m][n] = zero;

  // per-lane constant source swizzle: row&7 == lane>>3 for every issued chunk
  int lrow = lane >> 3;
  int coff = ((lane & 7) ^ lrow) * 16;

  for (int kk = 0; kk < 4; ++kk) {
#pragma unroll
    for (int s = 0; s < 4; ++s) {
      int rbase = w * 32 + s * 8;          // wave-uniform
      const char* ga = XA + (size_t)(rbase + lrow) * 512 + kk * 128 + coff;
      const char* gb = XB + (size_t)(rbase + lrow) * 512 + kk * 128 + coff;
      __builtin_amdgcn_global_load_lds(
          (const __attribute__((address_space(1))) void*)ga,
          (__attribute__((address_space(3))) void*)((char*)As + rbase * 128), 16, 0, 0);
      __builtin_amdgcn_global_load_lds(
          (const __attribute__((address_space(1))) void*)gb,
          (__attribute__((address_space(3))) void*)((char*)Bs + rbase * 128), 16, 0, 0);
    }
    __syncthreads();                       // drains vmcnt(0): staged data visible
    if (!skipw) {
#pragma unroll
      for (int ks = 0; ks < 2; ++ks) {
        bf16x8 a[4], b[4];
#pragma unroll
        for (int m = 0; m < 4; ++m)
          a[m] = *(const bf16x8*)((const char*)As + swz(wr * 64 + m * 16 + l15, ks * 64 + lk * 16));
        if (areuse) {
#pragma unroll
          for (int n = 0; n < 4; ++n) b[n] = a[n];
        } else {
#pragma unroll
          for (int n = 0; n < 4; ++n)
            b[n] = *(const bf16x8*)((const char*)Bs + swz(wc * 64 + n * 16 + l15, ks * 64 + lk * 16));
        }
#pragma unroll
        for (int m = 0; m < 4; ++m)
#pragma unroll
          for (int n = 0; n < 4; ++n)
            acc[m][n] = __builtin_amdgcn_mfma_f32_16x16x32_bf16(a[m], b[n], acc[m][n], 0, 0, 0);
      }
    }
    __syncthreads();
  }

  // epilogue: D = sqi + sqj - 2c ; K = sum_b exp(-D/b) via 1 exp2 + squarings
  float lsum = 0.f;
  if (!skipw) {
    const float c80 = 0.01803368801f;  // log2(e)/80
    float sqi[16], sqj[4];
#pragma unroll
    for (int m = 0; m < 4; ++m)
#pragma unroll
      for (int r = 0; r < 4; ++r) sqi[m * 4 + r] = SQi[wr * 64 + m * 16 + lk * 4 + r];
#pragma unroll
    for (int n = 0; n < 4; ++n) sqj[n] = SQj[wc * 64 + n * 16 + l15];

    bool sdiag = diag && (wr == wc);
#pragma unroll
    for (int m = 0; m < 4; ++m) {
#pragma unroll
      for (int n = 0; n < 4; ++n) {
#pragma unroll
        for (int r = 0; r < 4; ++r) {
          float cv = acc[m][n][r];
          float D = sqi[m * 4 + r] + sqj[n] - 2.f * cv;
          float e80 = exp2f(-c80 * D);     // exp(-D/80)
          float e40 = e80 * e80;
          float e20 = e40 * e40;
          float e10 = e20 * e20;
          float e5  = e10 * e10;
          float e2  = e5 * e5 * e10;       // exp(-D/2)
          float K = (e80 + e40) + (e20 + e10) + (e5 + e2);
          if (sdiag && m == n) {
            if (lk * 4 + r == l15) K = 6.0f;   // exact diagonal: D==0 -> K=6
          }
          lsum += K;
        }
      }
    }
    if (diag && w == 1) lsum *= 2.0f;      // stands in for skipped mirror wave
  }
#pragma unroll
  for (int off = 32; off; off >>= 1) lsum += __shfl_down(lsum, off, 64);
  if (lane == 0) wsum[w] = lsum;
  __syncthreads();
  if (t == 0) {
    float sgn = ((it < 2) == (jt < 2)) ? 1.0f : -1.0f;
    float tw  = diag ? 1.0f : 2.0f;        // off-diag tiles count twice (symmetry)
    part[bx] = sgn * tw * (wsum[0] + wsum[1] + wsum[2] + wsum[3]);
  }
}

// ---------------------------------------------------------------------------
// Kernel 3: deterministic final reduce of 2560 partials -> mean
// ---------------------------------------------------------------------------
__global__ __launch_bounds__(256) void k_reduce(const float* __restrict__ part,
                                                float* __restrict__ out) {
  __shared__ float wsum[4];
  int t = threadIdx.x;
  float s = 0.f;
#pragma unroll
  for (int i = 0; i < 10; ++i) s += part[i * 256 + t];
#pragma unroll
  for (int off = 32; off; off >>= 1) s += __shfl_down(s, off, 64);
  int lane = t & 63, w = t >> 6;
  if (lane == 0) wsum[w] = s;
  __syncthreads();
  if (t == 0) out[0] = (wsum[0] + wsum[1] + wsum[2] + wsum[3]) * (1.0f / 16777216.0f);
}

extern "C" void kernel_launch(void* const* d_in, const int* in_sizes, int n_in,
                              void* d_out, int out_size, void* d_ws, size_t ws_size,
                              hipStream_t stream) {
  (void)in_sizes; (void)n_in; (void)out_size; (void)ws_size;
  const float* src = (const float*)d_in[0];
  const float* tgt = (const float*)d_in[1];
  char* ws = (char*)d_ws;
  unsigned short* X = (unsigned short*)ws;                    // 67,108,864 B
  float* SQP  = (float*)(ws + 67108864);                      //  2,097,152 B (4 partials)
  float* PART = (float*)(ws + 67108864 + 2097152);            //     10,240 B

  hipLaunchKernelGGL(k_repack, dim3(8192), dim3(256), 0, stream, src, tgt, X, SQP);
  hipLaunchKernelGGL(k_mmd,    dim3(2560), dim3(256), 0, stream, X, SQP, PART);
  hipLaunchKernelGGL(k_reduce, dim3(1),    dim3(256), 0, stream, PART, (float*)d_out);
}